// Round 2
// baseline (1892.842 us; speedup 1.0000x reference)
//
#include <hip/hip_runtime.h>
#include <hip/hip_bf16.h>
#include <hip/hip_cooperative_groups.h>

namespace cg = cooperative_groups;

#define NDIM 2048
#define BS   64
#define NITR 25
#define NBLK 256   // blocks 0..127: U-half (GEMM1); 128..255: invM-half (GEMM2)

typedef __bf16 bf16_t;
typedef __bf16 bf16x4 __attribute__((ext_vector_type(4)));
typedef __bf16 bf16x8 __attribute__((ext_vector_type(8)));
typedef float  f32x4  __attribute__((ext_vector_type(4)));

// ---------------------------------------------------------------------------
// Convert H and y to bf16; zero traj[0].
// ---------------------------------------------------------------------------
__global__ void convert_kernel(const float* __restrict__ H, const float* __restrict__ y,
                               bf16_t* __restrict__ H16, bf16_t* __restrict__ y16,
                               float* __restrict__ traj0) {
  int idx = blockIdx.x * blockDim.x + threadIdx.x;
  float4 v = ((const float4*)H)[idx];
  bf16x4 o = {(bf16_t)v.x, (bf16_t)v.y, (bf16_t)v.z, (bf16_t)v.w};
  ((bf16x4*)H16)[idx] = o;
  if (idx < BS * NDIM / 4) {
    float4 w = ((const float4*)y)[idx];
    bf16x4 o2 = {(bf16_t)w.x, (bf16_t)w.y, (bf16_t)w.z, (bf16_t)w.w};
    ((bf16x4*)y16)[idx] = o2;
    ((float4*)traj0)[idx] = make_float4(0.f, 0.f, 0.f, 0.f);
  }
}

// ---------------------------------------------------------------------------
// Transpose + convert Dinv, U, invM -> bf16 transposed (NT-form B operands).
// ---------------------------------------------------------------------------
__global__ void transpose_kernel(const float* __restrict__ D, const float* __restrict__ U,
                                 const float* __restrict__ M,
                                 bf16_t* __restrict__ Dt, bf16_t* __restrict__ Ut,
                                 bf16_t* __restrict__ Mt) {
  __shared__ bf16_t tile[32][33];
  const float* src[3] = {D, U, M};
  bf16_t* dst[3] = {Dt, Ut, Mt};
  int tx = threadIdx.x, ty = threadIdx.y;
  int bx = blockIdx.x, by = blockIdx.y;
#pragma unroll
  for (int m = 0; m < 3; ++m) {
    __syncthreads();
#pragma unroll
    for (int i = 0; i < 4; ++i) {
      int r = by * 32 + ty + i * 8;
      int c = bx * 32 + tx;
      tile[ty + i * 8][tx] = (bf16_t)src[m][(size_t)r * NDIM + c];
    }
    __syncthreads();
#pragma unroll
    for (int i = 0; i < 4; ++i) {
      int r = bx * 32 + ty + i * 8;
      int c = by * 32 + tx;
      dst[m][(size_t)r * NDIM + c] = tile[tx][ty + i * 8];
    }
  }
}

// ---------------------------------------------------------------------------
// Stage a 16-column B panel (Bt rows n0..n0+15, full K=2048) into LDS in
// MFMA fragment order: frag F = c*64 + lane holds Bt[n0+(lane&15)][c*32 +
// (lane>>4)*8 .. +8].  ds_read_b128 at (c*64+lane)*16 is lane-contiguous ->
// zero bank conflicts.  64 KB total.
// ---------------------------------------------------------------------------
__device__ __forceinline__ void stage_panel(const bf16_t* __restrict__ Bt, int n0,
                                            bf16x8* __restrict__ lds) {
  __syncthreads();   // guard: prior panel reads complete before overwrite
#pragma unroll
  for (int i = 0; i < 16; ++i) {
    int F = i * 256 + threadIdx.x;
    int c = F >> 6, ln = F & 63;
    lds[F] = *(const bf16x8*)(Bt + (size_t)(n0 + (ln & 15)) * NDIM + c * 32 + ((ln >> 4) << 3));
  }
  __syncthreads();
}

// ---------------------------------------------------------------------------
// C[64,16] = A[64,2048] @ panel^T.  A direct from global (L2-hot), B from
// LDS fragment-ordered panel.  4 round-robin accumulators break the MFMA
// dependency chain; unroll 16 keeps ~16 global loads in flight.
// ---------------------------------------------------------------------------
__device__ __forceinline__ void gemm_panel(const bf16_t* __restrict__ A,
                                           const bf16x8* __restrict__ lds,
                                           f32x4* acc) {
  int lane = threadIdx.x & 63;
  int wave = threadIdx.x >> 6;
  const bf16x8* Ap = (const bf16x8*)(A + (size_t)(wave * 16 + (lane & 15)) * NDIM) + (lane >> 4);
  const bf16x8* Bp = lds + lane;
  acc[0] = acc[1] = acc[2] = acc[3] = (f32x4){0.f, 0.f, 0.f, 0.f};
#pragma unroll 16
  for (int c = 0; c < 64; ++c) {
    bf16x8 a = Ap[c * 4];        // A cols c*32 + q*8
    bf16x8 b = Bp[c * 64];       // frag-ordered panel chunk c
    acc[c & 3] = __builtin_amdgcn_mfma_f32_16x16x32_bf16(a, b, acc[c & 3], 0, 0, 0);
  }
}

// ---------------------------------------------------------------------------
// Persistent cooperative kernel: yMF, s_init, and 25 iterations with
// grid-wide sync.  Half 0 (blocks 0..127) pins the Ut panel; half 1 pins
// iMt.  Activation s/t round-trips global as bf16 between grid syncs.
// ---------------------------------------------------------------------------
__global__ __launch_bounds__(256, 1) void gs_persistent(
    const bf16_t* __restrict__ H16, const bf16_t* __restrict__ Dt16,
    const bf16_t* __restrict__ Ut16, const bf16_t* __restrict__ iMt16,
    const bf16_t* __restrict__ y16,
    bf16_t* __restrict__ yMF16, bf16_t* __restrict__ s16, bf16_t* __restrict__ t16,
    float* __restrict__ traj, float* __restrict__ s_final) {
  __shared__ bf16x8 panel[4096];   // 64 KB
  cg::grid_group grid = cg::this_grid();

  const int half  = blockIdx.x >> 7;
  const int n0    = (blockIdx.x & 127) * 16;
  const int lane  = threadIdx.x & 63;
  const int wave  = threadIdx.x >> 6;
  const int q     = lane >> 4;
  const int mlane = lane & 15;
  const int mrow  = wave * 16 + q * 4;   // + r
  const int col   = n0 + mlane;

  f32x4 acc[4];
  f32x4 yMFreg = {0.f, 0.f, 0.f, 0.f};

  // Phase A: half 0 computes yMF = y @ H^T (keeps fp32 slice in registers);
  // half 1 pre-stages its Dt panel concurrently.
  if (half == 0) {
    stage_panel(H16, n0, panel);
    gemm_panel(y16, panel, acc);
    f32x4 s = (acc[0] + acc[1]) + (acc[2] + acc[3]);
    yMFreg = s;
#pragma unroll
    for (int r = 0; r < 4; ++r)
      yMF16[(size_t)(mrow + r) * NDIM + col] = (bf16_t)s[r];
  } else {
    stage_panel(Dt16, n0, panel);
  }
  grid.sync();   // S1: yMF16 visible

  // Phase B: half 1 computes s_init = yMF @ Dinv; half 0 restages Ut.
  if (half == 1) {
    gemm_panel(yMF16, panel, acc);
    f32x4 s = (acc[0] + acc[1]) + (acc[2] + acc[3]);
#pragma unroll
    for (int r = 0; r < 4; ++r)
      s16[(size_t)(mrow + r) * NDIM + col] = (bf16_t)s[r];
  } else {
    stage_panel(Ut16, n0, panel);
  }
  grid.sync();   // S2: s16 visible

  if (half == 1) stage_panel(iMt16, n0, panel);   // overlaps half-0's first GEMM1

  for (int k = 1; k <= NITR; ++k) {
    if (half == 0) {
      gemm_panel(s16, panel, acc);
      f32x4 s = (acc[0] + acc[1]) + (acc[2] + acc[3]);
#pragma unroll
      for (int r = 0; r < 4; ++r)
        t16[(size_t)(mrow + r) * NDIM + col] = (bf16_t)(yMFreg[r] - s[r]);
    }
    grid.sync();   // t16 visible
    if (half == 1) {
      gemm_panel(t16, panel, acc);
      f32x4 s = (acc[0] + acc[1]) + (acc[2] + acc[3]);
      float* tr = traj + (size_t)k * BS * NDIM;
#pragma unroll
      for (int r = 0; r < 4; ++r) {
        size_t o = (size_t)(mrow + r) * NDIM + col;
        float v = s[r];
        tr[o] = v;
        s16[o] = (bf16_t)v;
        if (k == NITR) s_final[o] = v;
      }
    }
    grid.sync();   // s16 visible
  }
}

// ---------------------------------------------------------------------------
// Host driver: 3 launches.
// ---------------------------------------------------------------------------
extern "C" void kernel_launch(void* const* d_in, const int* in_sizes, int n_in,
                              void* d_out, int out_size, void* d_ws, size_t ws_size,
                              hipStream_t stream) {
  const float* y    = (const float*)d_in[2];
  const float* H    = (const float*)d_in[3];
  const float* Dinv = (const float*)d_in[4];
  const float* U    = (const float*)d_in[5];
  const float* invM = (const float*)d_in[6];

  float* out     = (float*)d_out;
  float* s_final = out;
  float* traj    = out + BS * NDIM;

  char* ws = (char*)d_ws;
  size_t off = 0;
  auto alloc = [&](size_t bytes) -> void* {
    void* p = ws + off;
    off += (bytes + 255) & ~(size_t)255;
    return p;
  };
  bf16_t* H16   = (bf16_t*)alloc((size_t)NDIM * NDIM * 2);
  bf16_t* Dt16  = (bf16_t*)alloc((size_t)NDIM * NDIM * 2);
  bf16_t* Ut16  = (bf16_t*)alloc((size_t)NDIM * NDIM * 2);
  bf16_t* iMt16 = (bf16_t*)alloc((size_t)NDIM * NDIM * 2);
  bf16_t* y16   = (bf16_t*)alloc((size_t)BS * NDIM * 2);
  bf16_t* yMF16 = (bf16_t*)alloc((size_t)BS * NDIM * 2);
  bf16_t* s16   = (bf16_t*)alloc((size_t)BS * NDIM * 2);
  bf16_t* t16   = (bf16_t*)alloc((size_t)BS * NDIM * 2);

  convert_kernel<<<(NDIM * NDIM / 4) / 256, 256, 0, stream>>>(H, y, H16, y16, traj);
  transpose_kernel<<<dim3(NDIM / 32, NDIM / 32), dim3(32, 8), 0, stream>>>(
      Dinv, U, invM, Dt16, Ut16, iMt16);

  void* args[] = {(void*)&H16, (void*)&Dt16, (void*)&Ut16, (void*)&iMt16, (void*)&y16,
                  (void*)&yMF16, (void*)&s16, (void*)&t16, (void*)&traj, (void*)&s_final};
  hipLaunchCooperativeKernel((void*)gs_persistent, dim3(NBLK), dim3(256), args, 0, stream);
}

// Round 3
// 486.932 us; speedup vs baseline: 3.8873x; 3.8873x over previous
//
#include <hip/hip_runtime.h>
#include <hip/hip_bf16.h>

#define NDIM 2048
#define BS   64
#define NITR 25
#define NM4  (NDIM * NDIM / 4)

typedef __bf16 bf16_t;
typedef __bf16 bf16x4 __attribute__((ext_vector_type(4)));
typedef __bf16 bf16x8 __attribute__((ext_vector_type(8)));
typedef float  f32x4  __attribute__((ext_vector_type(4)));

// ---------------------------------------------------------------------------
// Convert H, U, y to bf16 (row-major, no transpose); zero traj[0].
// grid: 2*NM4/256 blocks. idx < NM4 -> H, else U.
// ---------------------------------------------------------------------------
__global__ void convert_kernel(const float* __restrict__ H, const float* __restrict__ U,
                               const float* __restrict__ y,
                               bf16_t* __restrict__ H16, bf16_t* __restrict__ U16,
                               bf16_t* __restrict__ y16, float* __restrict__ traj0) {
  int idx = blockIdx.x * blockDim.x + threadIdx.x;
  const float* src = (idx < NM4) ? H : U;
  bf16_t* dst = (idx < NM4) ? H16 : U16;
  int i = (idx < NM4) ? idx : idx - NM4;
  float4 v = ((const float4*)src)[i];
  bf16x4 o = {(bf16_t)v.x, (bf16_t)v.y, (bf16_t)v.z, (bf16_t)v.w};
  ((bf16x4*)dst)[i] = o;
  if (idx < BS * NDIM / 4) {
    float4 w = ((const float4*)y)[idx];
    bf16x4 o2 = {(bf16_t)w.x, (bf16_t)w.y, (bf16_t)w.z, (bf16_t)w.w};
    ((bf16x4*)y16)[idx] = o2;
    ((float4*)traj0)[idx] = make_float4(0.f, 0.f, 0.f, 0.f);
  }
}

// ---------------------------------------------------------------------------
// Transpose + convert Dinv, invM -> bf16 transposed (NT-form B operands).
// ---------------------------------------------------------------------------
__global__ void transpose_kernel(const float* __restrict__ D, const float* __restrict__ M,
                                 bf16_t* __restrict__ Dt, bf16_t* __restrict__ Mt) {
  __shared__ bf16_t tile[32][33];
  const float* src[2] = {D, M};
  bf16_t* dst[2] = {Dt, Mt};
  int tx = threadIdx.x, ty = threadIdx.y;
  int bx = blockIdx.x, by = blockIdx.y;
#pragma unroll
  for (int m = 0; m < 2; ++m) {
    __syncthreads();
#pragma unroll
    for (int i = 0; i < 4; ++i)
      tile[ty + i * 8][tx] = (bf16_t)src[m][(size_t)(by * 32 + ty + i * 8) * NDIM + bx * 32 + tx];
    __syncthreads();
#pragma unroll
    for (int i = 0; i < 4; ++i)
      dst[m][(size_t)(bx * 32 + ty + i * 8) * NDIM + by * 32 + tx] = tile[tx][ty + i * 8];
  }
}

// ---------------------------------------------------------------------------
// 2048x2048x2048 NT GEMM (one-time): C = A @ Bt^T, all bf16, fp32 acc.
// m93-style: 256 blocks (16x16), 256 thr = 4 waves, 128x128 tile, BK=32.
// Wave quadrants 64x64; 16 MFMAs (4x4 of 16x16x32) per K-step.
// ---------------------------------------------------------------------------
__global__ __launch_bounds__(256) void wgemm(const bf16_t* __restrict__ A,
                                             const bf16_t* __restrict__ Bt,
                                             bf16_t* __restrict__ C) {
  __shared__ bf16_t As[128 * 32];  // row-major [r][k] 8 KB
  __shared__ bf16_t Bs[128 * 32];
  int tid = threadIdx.x, lane = tid & 63, wave = tid >> 6;
  int m0 = blockIdx.y * 128, n0 = blockIdx.x * 128;
  int wr = (wave >> 1) * 64, wc = (wave & 1) * 64;
  int q = lane >> 4, ml = lane & 15;

  f32x4 acc[4][4];
#pragma unroll
  for (int i = 0; i < 4; ++i)
#pragma unroll
    for (int j = 0; j < 4; ++j) acc[i][j] = (f32x4){0.f, 0.f, 0.f, 0.f};

  for (int k0 = 0; k0 < NDIM; k0 += 32) {
    __syncthreads();
#pragma unroll
    for (int i = 0; i < 2; ++i) {
      int f = i * 256 + tid, r = f >> 2, qq = f & 3;
      ((bf16x8*)As)[f] = *(const bf16x8*)(A + (size_t)(m0 + r) * NDIM + k0 + qq * 8);
      ((bf16x8*)Bs)[f] = *(const bf16x8*)(Bt + (size_t)(n0 + r) * NDIM + k0 + qq * 8);
    }
    __syncthreads();
    bf16x8 af[4], bfr[4];
#pragma unroll
    for (int i = 0; i < 4; ++i) {
      af[i]  = ((bf16x8*)As)[(wr + i * 16 + ml) * 4 + q];
      bfr[i] = ((bf16x8*)Bs)[(wc + i * 16 + ml) * 4 + q];
    }
#pragma unroll
    for (int i = 0; i < 4; ++i)
#pragma unroll
      for (int j = 0; j < 4; ++j)
        acc[i][j] = __builtin_amdgcn_mfma_f32_16x16x32_bf16(af[i], bfr[j], acc[i][j], 0, 0, 0);
  }
#pragma unroll
  for (int i = 0; i < 4; ++i)
#pragma unroll
    for (int j = 0; j < 4; ++j)
#pragma unroll
      for (int r = 0; r < 4; ++r)
        C[(size_t)(m0 + wr + i * 16 + q * 4 + r) * NDIM + n0 + wc + j * 16 + ml] =
            (bf16_t)acc[i][j][r];
}

// ---------------------------------------------------------------------------
// Skinny NT GEMM: C[64,16-per-block] = add + sign*(A[64,2048] @ Bt^T).
// 128 blocks x 512 thr (8 waves). Waves 0-3: M-stripes, K-half 0;
// waves 4-7: same stripes, K-half 1; LDS reduction joins halves.
// B panel staged in MFMA fragment order (conflict-free ds_read_b128).
// ---------------------------------------------------------------------------
__global__ __launch_bounds__(512) void gemm64(
    const bf16_t* __restrict__ A16, const bf16_t* __restrict__ Bt16,
    const float* __restrict__ add, float sign,
    float* __restrict__ outF32, float* __restrict__ outF32b,
    bf16_t* __restrict__ outB16) {
  __shared__ bf16x8 panel[4096];  // 64 KB: frag F=c*64+lane -> Bt[n0+(lane&15)][c*32+(lane>>4)*8..]
  __shared__ f32x4 red[256];      // K-half reduction scratch
  int tid = threadIdx.x, lane = tid & 63, wave = tid >> 6;
  int n0 = blockIdx.x * 16;
#pragma unroll
  for (int i = 0; i < 8; ++i) {
    int F = i * 512 + tid;
    int c = F >> 6, ln = F & 63;
    panel[F] = *(const bf16x8*)(Bt16 + (size_t)(n0 + (ln & 15)) * NDIM + c * 32 + ((ln >> 4) << 3));
  }
  __syncthreads();

  int ms = (wave & 3) * 16, kh = wave >> 2;
  const bf16x8* Ap = (const bf16x8*)(A16 + (size_t)(ms + (lane & 15)) * NDIM) + (lane >> 4) + kh * 128;
  const bf16x8* Bp = panel + lane + kh * 32 * 64;

  f32x4 acc[4];
  acc[0] = acc[1] = acc[2] = acc[3] = (f32x4){0.f, 0.f, 0.f, 0.f};
#pragma unroll
  for (int c = 0; c < 32; ++c) {
    bf16x8 a = Ap[c * 4];
    bf16x8 b = Bp[c * 64];
    acc[c & 3] = __builtin_amdgcn_mfma_f32_16x16x32_bf16(a, b, acc[c & 3], 0, 0, 0);
  }
  f32x4 s = (acc[0] + acc[1]) + (acc[2] + acc[3]);

  if (wave >= 4) red[(wave & 3) * 64 + lane] = s;
  __syncthreads();
  if (wave < 4) {
    s += red[wave * 64 + lane];
    int mrow = ms + (lane >> 4) * 4, col = n0 + (lane & 15);
#pragma unroll
    for (int r = 0; r < 4; ++r) {
      size_t o = (size_t)(mrow + r) * NDIM + col;
      float v = sign * s[r];
      if (add) v += add[o];
      if (outF32)  outF32[o]  = v;
      if (outF32b) outF32b[o] = v;
      if (outB16)  outB16[o]  = (bf16_t)v;
    }
  }
}

// ---------------------------------------------------------------------------
// Host driver: 31 launches.
//   s' = (yMF - s@U)@invM  ==  c - s@W,  W = U@invM, c = yMF@invM.
// NT forms: Wt = iMt16 @ U16^T  (Wt[m][n] = W[n][m]); iteration Bt = Wt.
// ---------------------------------------------------------------------------
extern "C" void kernel_launch(void* const* d_in, const int* in_sizes, int n_in,
                              void* d_out, int out_size, void* d_ws, size_t ws_size,
                              hipStream_t stream) {
  const float* y    = (const float*)d_in[2];
  const float* H    = (const float*)d_in[3];
  const float* Dinv = (const float*)d_in[4];
  const float* U    = (const float*)d_in[5];
  const float* invM = (const float*)d_in[6];

  float* out     = (float*)d_out;
  float* s_final = out;
  float* traj    = out + BS * NDIM;

  char* ws = (char*)d_ws;
  size_t off = 0;
  auto alloc = [&](size_t bytes) -> void* {
    void* p = ws + off;
    off += (bytes + 255) & ~(size_t)255;
    return p;
  };
  bf16_t* U16   = (bf16_t*)alloc((size_t)NDIM * NDIM * 2);
  bf16_t* Dt16  = (bf16_t*)alloc((size_t)NDIM * NDIM * 2);
  bf16_t* iMt16 = (bf16_t*)alloc((size_t)NDIM * NDIM * 2);
  bf16_t* HW16  = (bf16_t*)alloc((size_t)NDIM * NDIM * 2);  // H16, then reused for Wt16
  bf16_t* y16   = (bf16_t*)alloc((size_t)BS * NDIM * 2);
  bf16_t* yMF16 = (bf16_t*)alloc((size_t)BS * NDIM * 2);
  bf16_t* sA    = (bf16_t*)alloc((size_t)BS * NDIM * 2);
  bf16_t* sB    = (bf16_t*)alloc((size_t)BS * NDIM * 2);
  float*  c32   = (float*)alloc((size_t)BS * NDIM * 4);

  convert_kernel<<<2 * NM4 / 256, 256, 0, stream>>>(H, U, y, HW16, U16, y16, traj);
  transpose_kernel<<<dim3(NDIM / 32, NDIM / 32), dim3(32, 8), 0, stream>>>(Dinv, invM, Dt16, iMt16);

  dim3 sgrid(NDIM / 16), sblk(512);
  // yMF = y @ H^T  (H16 used here, then its buffer is recycled for Wt)
  gemm64<<<sgrid, sblk, 0, stream>>>(y16, HW16, nullptr, 1.f, nullptr, nullptr, yMF16);
  // Wt = iMt16 @ U16^T  -> overwrite HW16
  wgemm<<<dim3(16, 16), 256, 0, stream>>>(iMt16, U16, HW16);
  // c = yMF @ invM (fp32 addend)
  gemm64<<<sgrid, sblk, 0, stream>>>(yMF16, iMt16, nullptr, 1.f, c32, nullptr, nullptr);
  // s_init = yMF @ Dinv
  gemm64<<<sgrid, sblk, 0, stream>>>(yMF16, Dt16, nullptr, 1.f, nullptr, nullptr, sA);

  bf16_t* scur = sA;
  bf16_t* snxt = sB;
  for (int k = 1; k <= NITR; ++k) {
    float* f32b = (k == NITR) ? s_final : nullptr;
    // s' = c - s @ W  (product negated, c added)
    gemm64<<<sgrid, sblk, 0, stream>>>(scur, HW16, c32, -1.f,
                                       traj + (size_t)k * BS * NDIM, f32b, snxt);
    bf16_t* tmp = scur; scur = snxt; snxt = tmp;
  }
}

// Round 4
// 425.529 us; speedup vs baseline: 4.4482x; 1.1443x over previous
//
#include <hip/hip_runtime.h>
#include <hip/hip_bf16.h>

#define NDIM 2048
#define BS   64
#define NITR 25
#define NM4  (NDIM * NDIM / 4)

typedef __bf16 bf16_t;
typedef __bf16 bf16x4 __attribute__((ext_vector_type(4)));
typedef __bf16 bf16x8 __attribute__((ext_vector_type(8)));
typedef float  f32x4  __attribute__((ext_vector_type(4)));

// ---------------------------------------------------------------------------
// prep: convert H,U,y -> bf16 row-major; transpose+convert Dinv,invM -> Dt,iMt;
// zero traj[0].  Blocks 0..8191: convert; 8192..12287: transpose.
// ---------------------------------------------------------------------------
__global__ __launch_bounds__(256) void prep(
    const float* __restrict__ H, const float* __restrict__ U,
    const float* __restrict__ Dinv, const float* __restrict__ invM,
    const float* __restrict__ y,
    bf16_t* __restrict__ H16, bf16_t* __restrict__ U16,
    bf16_t* __restrict__ Dt, bf16_t* __restrict__ iMt,
    bf16_t* __restrict__ y16, float* __restrict__ traj0) {
  __shared__ bf16_t tile[32][33];
  int b = blockIdx.x, tid = threadIdx.x;
  if (b < 8192) {
    int idx = b * 256 + tid;
    const float* src = (idx < NM4) ? H : U;
    bf16_t* dst = (idx < NM4) ? H16 : U16;
    int i = (idx < NM4) ? idx : idx - NM4;
    float4 v = ((const float4*)src)[i];
    bf16x4 o = {(bf16_t)v.x, (bf16_t)v.y, (bf16_t)v.z, (bf16_t)v.w};
    ((bf16x4*)dst)[i] = o;
    if (idx < BS * NDIM / 4) {
      float4 w = ((const float4*)y)[idx];
      bf16x4 o2 = {(bf16_t)w.x, (bf16_t)w.y, (bf16_t)w.z, (bf16_t)w.w};
      ((bf16x4*)y16)[idx] = o2;
      ((float4*)traj0)[idx] = make_float4(0.f, 0.f, 0.f, 0.f);
    }
  } else {
    int id = b - 8192;
    int bx = id & 63, by = id >> 6;
    int tx = tid & 31, ty = tid >> 5;
    const float* src[2] = {Dinv, invM};
    bf16_t* dst[2] = {Dt, iMt};
#pragma unroll
    for (int m = 0; m < 2; ++m) {
      __syncthreads();
#pragma unroll
      for (int i = 0; i < 4; ++i)
        tile[ty + i * 8][tx] =
            (bf16_t)src[m][(size_t)(by * 32 + ty + i * 8) * NDIM + bx * 32 + tx];
      __syncthreads();
#pragma unroll
      for (int i = 0; i < 4; ++i)
        dst[m][(size_t)(bx * 32 + ty + i * 8) * NDIM + by * 32 + tx] = tile[tx][ty + i * 8];
    }
  }
}

// ---------------------------------------------------------------------------
// Skinny NT GEMM role: C[64, 16] = add + sign*(A[64,2048] @ Bt^T cols n0..+15).
// 4 waves = 4 M-stripes of 16, full K per wave.  B panel staged into LDS in
// MFMA fragment order (slot F=c*64+lane) -> conflict-free ds_read/write_b128.
// ---------------------------------------------------------------------------
__device__ __forceinline__ void skinny_role(
    const bf16_t* __restrict__ A, const bf16_t* __restrict__ Bt, int n0, char* smem,
    const float* __restrict__ add, float sign,
    float* o32, float* o32b, bf16_t* o16) {
  bf16x8* panel = (bf16x8*)smem;  // 4096 slots = 64 KB
  int tid = threadIdx.x, lane = tid & 63, wave = tid >> 6;
#pragma unroll
  for (int i = 0; i < 16; ++i) {
    int F = i * 256 + tid, c = F >> 6, ln = F & 63;
    panel[F] = *(const bf16x8*)(Bt + (size_t)(n0 + (ln & 15)) * NDIM + c * 32 + ((ln >> 4) << 3));
  }
  __syncthreads();
  int ml = lane & 15, q = lane >> 4;
  const bf16x8* Ap = (const bf16x8*)(A + (size_t)(wave * 16 + ml) * NDIM) + q;
  const bf16x8* Bp = panel + lane;
  f32x4 acc[4];
  acc[0] = acc[1] = acc[2] = acc[3] = (f32x4){0.f, 0.f, 0.f, 0.f};
#pragma unroll 16
  for (int c = 0; c < 64; ++c) {
    bf16x8 a = Ap[c * 4];
    bf16x8 b = Bp[c * 64];
    acc[c & 3] = __builtin_amdgcn_mfma_f32_16x16x32_bf16(a, b, acc[c & 3], 0, 0, 0);
  }
  f32x4 s = (acc[0] + acc[1]) + (acc[2] + acc[3]);
  int mrow = wave * 16 + q * 4, col = n0 + ml;
#pragma unroll
  for (int r = 0; r < 4; ++r) {
    size_t o = (size_t)(mrow + r) * NDIM + col;
    float v = sign * s[r];
    if (add) v += add[o];
    if (o32)  o32[o]  = v;
    if (o32b) o32b[o] = v;
    if (o16)  o16[o]  = (bf16_t)v;
  }
}

// ---------------------------------------------------------------------------
// 2048^3 NT GEMM role (128x128 tile, BK=32, 16 MFMAs/K-step).  LDS in
// fragment order: slot S = rowgroup*64 + (ml + 16*q) -> staging writes and
// fragment reads are both lane-consecutive 16B (zero bank conflicts).
// ---------------------------------------------------------------------------
__device__ __forceinline__ void wgemm_role(
    const bf16_t* __restrict__ A, const bf16_t* __restrict__ Bt,
    bf16_t* __restrict__ C, int blk, char* smem) {
  bf16x8* As = (bf16x8*)smem;           // 512 slots (8 KB)
  bf16x8* Bs = (bf16x8*)(smem + 8192);  // 512 slots
  int tid = threadIdx.x, lane = tid & 63, wave = tid >> 6;
  int m0 = (blk >> 4) * 128, n0 = (blk & 15) * 128;
  int wr16 = (wave >> 1) * 4, wc16 = (wave & 1) * 4;  // row-group bases (/16)
  int ml = lane & 15, q = lane >> 4;

  f32x4 acc[4][4];
#pragma unroll
  for (int i = 0; i < 4; ++i)
#pragma unroll
    for (int j = 0; j < 4; ++j) acc[i][j] = (f32x4){0.f, 0.f, 0.f, 0.f};

  for (int k0 = 0; k0 < NDIM; k0 += 32) {
    __syncthreads();
#pragma unroll
    for (int i = 0; i < 2; ++i) {
      int S = i * 256 + tid, g = S >> 6, ln = S & 63;
      int row = g * 16 + (ln & 15), kq = (ln >> 4) << 3;
      As[S] = *(const bf16x8*)(A  + (size_t)(m0 + row) * NDIM + k0 + kq);
      Bs[S] = *(const bf16x8*)(Bt + (size_t)(n0 + row) * NDIM + k0 + kq);
    }
    __syncthreads();
    bf16x8 af[4], bfr[4];
#pragma unroll
    for (int i = 0; i < 4; ++i) {
      af[i]  = As[(wr16 + i) * 64 + lane];
      bfr[i] = Bs[(wc16 + i) * 64 + lane];
    }
#pragma unroll
    for (int i = 0; i < 4; ++i)
#pragma unroll
      for (int j = 0; j < 4; ++j)
        acc[i][j] = __builtin_amdgcn_mfma_f32_16x16x32_bf16(af[i], bfr[j], acc[i][j], 0, 0, 0);
  }
  int wr = wr16 * 16, wc = wc16 * 16;
#pragma unroll
  for (int i = 0; i < 4; ++i)
#pragma unroll
    for (int j = 0; j < 4; ++j)
#pragma unroll
      for (int r = 0; r < 4; ++r)
        C[(size_t)(m0 + wr + i * 16 + q * 4 + r) * NDIM + n0 + wc + j * 16 + ml] =
            (bf16_t)acc[i][j][r];
}

// ---------------------------------------------------------------------------
// mega1 (640 blocks): yMF = y@H^T (128 skinny blocks) || W_rm = U@invM
// (256 wgemm blocks) || Wt = (U@invM)^T (256 wgemm blocks).
// ---------------------------------------------------------------------------
__global__ __launch_bounds__(256) void mega1(
    const bf16_t* __restrict__ U16, const bf16_t* __restrict__ iMt16,
    const bf16_t* __restrict__ y16, const bf16_t* __restrict__ H16,
    bf16_t* __restrict__ Wrm, bf16_t* __restrict__ Wt, bf16_t* __restrict__ yMF16) {
  __shared__ char smem[65536];
  int b = blockIdx.x;
  if (b < 128)
    skinny_role(y16, H16, b * 16, smem, nullptr, 1.f, nullptr, nullptr, yMF16);
  else if (b < 384)
    wgemm_role(U16, iMt16, Wrm, b - 128, smem);   // W_rm[m][n] = sum U[m][k] iMt[n][k]
  else
    wgemm_role(iMt16, U16, Wt, b - 384, smem);    // Wt[m][n]  = W[n][m]
}

// ---------------------------------------------------------------------------
// mega2 (512 blocks): c = yMF@invM (128) || x0 = yMF@Dinv (128, -> zA rows
// 0..63) || W2t = Wt @ W_rm^T(NT) = (W@W)^T (256 wgemm blocks).
// ---------------------------------------------------------------------------
__global__ __launch_bounds__(256) void mega2(
    const bf16_t* __restrict__ Wt, const bf16_t* __restrict__ Wrm,
    const bf16_t* __restrict__ yMF16, const bf16_t* __restrict__ iMt16,
    const bf16_t* __restrict__ Dt16,
    bf16_t* __restrict__ W2t, float* __restrict__ c32, bf16_t* __restrict__ c16,
    bf16_t* __restrict__ zA) {
  __shared__ char smem[65536];
  int b = blockIdx.x;
  if (b < 128)
    skinny_role(yMF16, iMt16, b * 16, smem, nullptr, 1.f, c32, nullptr, c16);
  else if (b < 256)
    skinny_role(yMF16, Dt16, (b - 128) * 16, smem, nullptr, 1.f, nullptr, nullptr, zA);
  else
    wgemm_role(Wt, Wrm, W2t, b - 256, smem);
}

// ---------------------------------------------------------------------------
// Dual skinny node (256 blocks): two independent [64,2048] GEMMs against one
// B panel (block b: n-panel b>>1, M-half b&1).  Shared fp32 addend.
// ---------------------------------------------------------------------------
__global__ __launch_bounds__(256) void skinny_dual(
    const bf16_t* __restrict__ A0, const bf16_t* __restrict__ A1,
    const bf16_t* __restrict__ Bt, const float* __restrict__ add, float sign,
    float* o32_0, float* o32_1, float* o32b_1,
    bf16_t* o16_0, bf16_t* o16_1) {
  __shared__ char smem[65536];
  int b = blockIdx.x, p = b >> 1, mh = b & 1;
  skinny_role(mh ? A1 : A0, Bt, p * 16, smem, add, sign,
              mh ? o32_1 : o32_0, mh ? o32b_1 : nullptr, mh ? o16_1 : o16_0);
}

// ---------------------------------------------------------------------------
// Host driver: 16 graph nodes.
//   x_{k+1} = c - x_k W        (W = U@invM, c = yMF@invM)
//   x_{k+2} = c2 + x_k W2      (W2 = W^2,  c2 = c - cW)
// Chains [x_even; x_odd] stacked as M=128 -> 12 iteration nodes for x_2..x_25.
// ---------------------------------------------------------------------------
extern "C" void kernel_launch(void* const* d_in, const int* in_sizes, int n_in,
                              void* d_out, int out_size, void* d_ws, size_t ws_size,
                              hipStream_t stream) {
  const float* y    = (const float*)d_in[2];
  const float* H    = (const float*)d_in[3];
  const float* Dinv = (const float*)d_in[4];
  const float* U    = (const float*)d_in[5];
  const float* invM = (const float*)d_in[6];

  float* out     = (float*)d_out;
  float* s_final = out;
  float* traj    = out + BS * NDIM;

  char* ws = (char*)d_ws;
  size_t off = 0;
  auto alloc = [&](size_t bytes) -> void* {
    void* p = ws + off;
    off += (bytes + 255) & ~(size_t)255;
    return p;
  };
  bf16_t* U16   = (bf16_t*)alloc((size_t)NDIM * NDIM * 2);
  bf16_t* Dt16  = (bf16_t*)alloc((size_t)NDIM * NDIM * 2);
  bf16_t* iMt16 = (bf16_t*)alloc((size_t)NDIM * NDIM * 2);
  bf16_t* H16   = (bf16_t*)alloc((size_t)NDIM * NDIM * 2);  // reused as W2t after mega1
  bf16_t* Wrm   = (bf16_t*)alloc((size_t)NDIM * NDIM * 2);
  bf16_t* Wt    = (bf16_t*)alloc((size_t)NDIM * NDIM * 2);
  bf16_t* y16   = (bf16_t*)alloc((size_t)BS * NDIM * 2);
  bf16_t* yMF16 = (bf16_t*)alloc((size_t)BS * NDIM * 2);
  bf16_t* c16   = (bf16_t*)alloc((size_t)BS * NDIM * 2);
  float*  c32   = (float*)alloc((size_t)BS * NDIM * 4);
  float*  c2_32 = (float*)alloc((size_t)BS * NDIM * 4);
  bf16_t* zA    = (bf16_t*)alloc((size_t)2 * BS * NDIM * 2);  // [128,2048]
  bf16_t* zB    = (bf16_t*)alloc((size_t)2 * BS * NDIM * 2);
  bf16_t* W2t   = H16;

  // N1: convert + transpose + zero traj[0]
  prep<<<12288, 256, 0, stream>>>(H, U, Dinv, invM, y, H16, U16, Dt16, iMt16, y16, traj);
  // N2: yMF || W_rm || Wt
  mega1<<<640, 256, 0, stream>>>(U16, iMt16, y16, H16, Wrm, Wt, yMF16);
  // N3: c || x0 (-> zA rows 0..63) || W2t
  mega2<<<512, 256, 0, stream>>>(Wt, Wrm, yMF16, iMt16, Dt16, W2t, c32, c16, zA);
  // N4: c2 = c - cW  ||  x1 = c - x0 W  (-> traj[1], zA rows 64..127)
  skinny_dual<<<256, 256, 0, stream>>>(c16, zA, Wt, c32, -1.f,
                                       c2_32, traj + (size_t)BS * NDIM, nullptr,
                                       nullptr, zA + (size_t)64 * NDIM);
  // N5..N16: 12 x dual-chain step with W2
  bf16_t* zcur = zA;
  bf16_t* znxt = zB;
  for (int j = 1; j <= 12; ++j) {
    skinny_dual<<<256, 256, 0, stream>>>(
        zcur, zcur + (size_t)64 * NDIM, W2t, c2_32, 1.f,
        traj + (size_t)(2 * j) * BS * NDIM, traj + (size_t)(2 * j + 1) * BS * NDIM,
        (j == 12) ? s_final : nullptr,
        znxt, znxt + (size_t)64 * NDIM);
    bf16_t* tmp = zcur; zcur = znxt; znxt = tmp;
  }
}